// Round 4
// baseline (473.798 us; speedup 1.0000x reference)
//
#include <hip/hip_runtime.h>

// SpikeLatencyLIFEncoder, memset + scatter:
// Each element spikes at most once (latency encoding), so the 419 MB output
// is zeros except <=1M ones. hipMemsetAsync (the rocclr fill path, measured
// 6.2 TB/s in-profile) zeros the buffer; one small kernel runs the exact
// fp32 LIF recurrence and scatter-stores 1.0f at the first-spike position.
// Theoretical floor: 419 MB / 6.2 TB/s = 68 us + ~15 us compute/scatter.

#define SEQ_LEN 100

__global__ __launch_bounds__(256) void lif_scatter_ones(
    const float4* __restrict__ in, float* __restrict__ out, int n4, int n) {
    int i = blockIdx.x * blockDim.x + threadIdx.x;
    if (i >= n4) return;

    float4 I4 = in[i];
    float Iv[4] = {I4.x, I4.y, I4.z, I4.w};

    #pragma unroll
    for (int c = 0; c < 4; ++c) {
        float Ic = Iv[c];
        float v = 0.0f;
        int t = 0;
        for (; t < SEQ_LEN; ++t) {
            // v = v + 0.1f * ((0.0f - v) + I)  -- exact fp32, no FMA contraction
            float d = __fadd_rn(__fsub_rn(0.0f, v), Ic);
            v = __fadd_rn(v, __fmul_rn(0.1f, d));
            if (v > 1.0f) break;  // == (v - 1.0f) > 0.0f in fp32
        }
        if (t < SEQ_LEN) {
            // first (and only) spike for this element
            out[(size_t)t * (size_t)n + (size_t)(4 * i + c)] = 1.0f;
        }
    }
}

extern "C" void kernel_launch(void* const* d_in, const int* in_sizes, int n_in,
                              void* d_out, int out_size, void* d_ws, size_t ws_size,
                              hipStream_t stream) {
    const float* in = (const float*)d_in[0];
    int n = in_sizes[0];   // 256*4096 = 1,048,576
    int n4 = n / 4;        // 262,144 float4 loads

    // Zero the whole output via the driver fill path (6.2 TB/s measured).
    hipMemsetAsync(d_out, 0, (size_t)out_size * sizeof(float), stream);

    int threads = 256;
    int blocks = (n4 + threads - 1) / threads;  // 1024
    lif_scatter_ones<<<blocks, threads, 0, stream>>>(
        (const float4*)in, (float*)d_out, n4, n);
}

// Round 5
// 432.411 us; speedup vs baseline: 1.0957x; 1.0957x over previous
//
#include <hip/hip_runtime.h>

// SpikeLatencyLIFEncoder, monolithic (best measured structure, R1=441us):
// per-float4 thread computes first-spike times then streams 100 coalesced
// nontemporal float4 stores. Model: dur_us = ~365us fixed harness overhead
// (1.678GB poison fill etc.) + ~75us ours (68us write floor for 419MB).
//
// Refinements vs R1:
//  - branchless fixed-100 recurrence, 4 components interleaved (ILP); the
//    early-exit saved nothing (waves run max-lane iterations; ~50% of
//    elements never spike). Reset omitted: only FIRST crossing matters.
//  - nontemporal stores: 419MB stream should not allocate in L2.

#define SEQ_LEN 100

typedef float nfloat4 __attribute__((ext_vector_type(4)));

__global__ __launch_bounds__(256) void lif_latency_kernel(
    const float4* __restrict__ in, nfloat4* __restrict__ out, int n4) {
    int i = blockIdx.x * blockDim.x + threadIdx.x;
    if (i >= n4) return;

    float4 I4 = in[i];
    float Iv[4] = {I4.x, I4.y, I4.z, I4.w};
    float v[4] = {0.0f, 0.0f, 0.0f, 0.0f};
    int ts[4] = {SEQ_LEN, SEQ_LEN, SEQ_LEN, SEQ_LEN};

    // Exact fp32 recurrence (no FMA contraction): v += 0.1f*((0-v)+I).
    // 4 independent chains interleaved; record first t where v > 1.
    for (int t = 0; t < SEQ_LEN; ++t) {
        #pragma unroll
        for (int c = 0; c < 4; ++c) {
            float d = __fadd_rn(__fsub_rn(0.0f, v[c]), Iv[c]);
            v[c] = __fadd_rn(v[c], __fmul_rn(0.1f, d));
            // first crossing only; min keeps the earliest t
            ts[c] = (v[c] > 1.0f && ts[c] == SEQ_LEN) ? t : ts[c];
        }
    }

    nfloat4* o = out + i;
    #pragma unroll 4
    for (int t = 0; t < SEQ_LEN; ++t) {
        nfloat4 val;
        val.x = (t == ts[0]) ? 1.0f : 0.0f;
        val.y = (t == ts[1]) ? 1.0f : 0.0f;
        val.z = (t == ts[2]) ? 1.0f : 0.0f;
        val.w = (t == ts[3]) ? 1.0f : 0.0f;
        __builtin_nontemporal_store(val, &o[(size_t)t * n4]);
    }
}

extern "C" void kernel_launch(void* const* d_in, const int* in_sizes, int n_in,
                              void* d_out, int out_size, void* d_ws, size_t ws_size,
                              hipStream_t stream) {
    const float* in = (const float*)d_in[0];
    int n = in_sizes[0];   // 256*4096 = 1,048,576
    int n4 = n / 4;        // 262,144
    int threads = 256;
    int blocks = (n4 + threads - 1) / threads;  // 1024
    lif_latency_kernel<<<blocks, threads, 0, stream>>>(
        (const float4*)in, (nfloat4*)d_out, n4);
}